// Round 16
// baseline (1383.079 us; speedup 1.0000x reference)
//
#include <hip/hip_runtime.h>

static constexpr int NB   = 384;
static constexpr int SEQL = 256;
static constexpr int NROWS = NB * SEQL; // 98304

typedef short bf16x8 __attribute__((ext_vector_type(8)));
typedef float f32x4  __attribute__((ext_vector_type(4)));

union B8u {
    bf16x8 v;
    ushort us[8];
    uint4  q;
};

union F4u { float4 v; float f[4]; };

__device__ inline ushort f2bf(float f) {
    uint u = __float_as_uint(f);
    uint r = u + 0x7FFFu + ((u >> 16) & 1u);
    return (ushort)(r >> 16);
}

__device__ inline void split8(float4 a, float4 b, B8u& hi, B8u& lo) {
    float f[8] = {a.x, a.y, a.z, a.w, b.x, b.y, b.z, b.w};
    #pragma unroll
    for (int i = 0; i < 8; ++i) {
        ushort h = f2bf(f[i]);
        hi.us[i] = h;
        float fh = __uint_as_float(((uint)h) << 16);
        lo.us[i] = f2bf(f[i] - fh);
    }
}

__device__ inline float fast_rcp(float x) {
    float r = __builtin_amdgcn_rcpf(x);
    return r * (2.f - x * r);
}
__device__ inline float fast_sig(float x) {
    float e = __expf(fminf(-x, 80.f));
    return fast_rcp(1.f + e);
}
__device__ inline float fast_tanh(float a) {
    float e = __expf(fminf(2.f * fabsf(a), 80.f));
    float t = 1.f - 2.f * fast_rcp(1.f + e);
    return (a >= 0.f) ? t : -t;
}

__device__ inline void split1(const float* s, ushort* h, ushort* l, int i) {
    float f = s[i];
    ushort hh = f2bf(f);
    h[i] = hh;
    l[i] = f2bf(f - __uint_as_float(((uint)hh) << 16));
}

// ---------------------------------------------------------------------------
// All 9 weight splits in ONE launch.
// ---------------------------------------------------------------------------
__global__ __launch_bounds__(256) void split_all(
    const float* s0, const float* s1, const float* s2, const float* s3,
    const float* s4, const float* s5, const float* s6, const float* s7,
    const float* s8,
    ushort* h0, ushort* h1, ushort* h2, ushort* h3, ushort* h4,
    ushort* h5, ushort* h6, ushort* h7, ushort* h8,
    ushort* l0, ushort* l1, ushort* l2, ushort* l3, ushort* l4,
    ushort* l5, ushort* l6, ushort* l7, ushort* l8)
{
    const int b = blockIdx.x;
    const float* s; ushort* h; ushort* l; int base;
    if      (b < 256) { s = s0; h = h0; l = l0; base = 0; }
    else if (b < 512) { s = s1; h = h1; l = l1; base = 256; }
    else if (b < 608) { s = s2; h = h2; l = l2; base = 512; }
    else if (b < 656) { s = s3; h = h3; l = l3; base = 608; }
    else if (b < 704) { s = s4; h = h4; l = l4; base = 656; }
    else if (b < 720) { s = s5; h = h5; l = l5; base = 704; }
    else if (b < 736) { s = s6; h = h6; l = l6; base = 720; }
    else if (b < 784) { s = s7; h = h7; l = l7; base = 736; }
    else              { s = s8; h = h8; l = l8; base = 784; }
    split1(s, h, l, (b - base) * 256 + threadIdx.x);
}

// ---------------------------------------------------------------------------
// Featurize + GRU layer-0 input projection:  X[(t*NB+b)*192 + j]
// ---------------------------------------------------------------------------
__global__ __launch_bounds__(192) void featproj_kernel(
    const float* __restrict__ x, const float* __restrict__ emb,
    const float* __restrict__ wih0, const float* __restrict__ bih0,
    float* __restrict__ X)
{
    __shared__ float F[32][33];
    const int tid = threadIdx.x;
    const int m0  = blockIdx.x * 32;

    if (tid < 96) {
        const int r   = tid & 31;
        const int grp = tid >> 5;
        const int m   = m0 + r;
        const int b   = m % NB;
        const int l   = m / NB;
        const float* xb = x + (size_t)b * (3 * SEQL);
        const float x0 = xb[l], x1 = xb[SEQL + l], x2 = xb[2 * SEQL + l];
        const bool is_angle = (b % 3) == 2;
        float o[10];
        if (is_angle) {
            if (grp < 2) {
                const float a = (grp == 0) ? x0 : x1;
                #pragma unroll
                for (int c = 0; c < 10; ++c) { float d = (float)(c + 1) - a; o[c] = __expf(-d * d); }
            } else {
                float t0 = 1.f, t1 = x2;
                o[0] = 1.f; o[1] = x2;
                #pragma unroll
                for (int c = 2; c < 10; ++c) { float t = 2.f * x2 * t1 - t0; o[c] = t; t0 = t1; t1 = t; }
            }
        } else {
            if (grp < 2) {
                const float xv = (grp == 0) ? x0 : x1;
                int idx = (int)xv; idx = idx < 0 ? 0 : (idx > 118 ? 118 : idx);
                #pragma unroll
                for (int c = 0; c < 10; ++c) o[c] = emb[idx * 10 + c];
            } else {
                #pragma unroll
                for (int c = 0; c < 10; ++c) { float d = (float)(c + 1) - x2; o[c] = __expf(-d * d); }
            }
        }
        #pragma unroll
        for (int c = 0; c < 10; ++c) F[r][grp * 10 + c] = o[c];
    }
    __syncthreads();

    float w[30];
    #pragma unroll
    for (int k = 0; k < 30; ++k) w[k] = wih0[tid * 30 + k];
    const float bj = bih0[tid];
    for (int r = 0; r < 32; ++r) {
        float acc = bj;
        #pragma unroll
        for (int k = 0; k < 30; ++k) acc += F[r][k] * w[k];
        X[(size_t)(m0 + r) * 192 + tid] = acc;
    }
}

// ---------------------------------------------------------------------------
// GRU recurrence + FUSED next-layer input projection.
// 16 batch rows/block, 4 waves. At step t, B-frags hold h[t-1] -- exactly the
// operand the next layer's projection needs: 18 extra MFMAs (indep accum,
// A-frags = pre-split Wih in regs) produce gi_next[t-1] = bih + h[t-1]@Wih.T,
// written straight to Xout. Tail pass handles t=SEQL-1. Layers 0/1 skip the
// h-store entirely (Y=nullptr). 1 wave/SIMD -> VGPR budget 512, no spill.
// ---------------------------------------------------------------------------
__global__ __launch_bounds__(256, 1) void gru_mfma(
    const float* __restrict__ X, const ushort* __restrict__ WhhHi,
    const ushort* __restrict__ WhhLo, const float* __restrict__ bhh,
    float* __restrict__ Y, int out_batch_major,
    const ushort* __restrict__ WIhi, const ushort* __restrict__ WIlo,
    const float* __restrict__ bih_next, float* __restrict__ Xout, int do_proj)
{
    constexpr int PAD = 88;
    __shared__ __align__(16) ushort Hh[2][16][PAD];
    __shared__ __align__(16) ushort Hl[2][16][PAD];

    const int tid  = threadIdx.x;
    const int wt   = tid >> 6;
    const int lane = tid & 63;
    const int c    = lane & 15;
    const int g    = lane >> 4;
    const int b0   = blockIdx.x * 16;

    B8u awh[3][2], awl[3][2];
    #pragma unroll
    for (int gam = 0; gam < 3; ++gam)
        #pragma unroll
        for (int ks = 0; ks < 2; ++ks) {
            size_t off = (size_t)(64 * gam + 16 * wt + c) * 64 + 32 * ks + 8 * g;
            awh[gam][ks].q = *(const uint4*)(WhhHi + off);
            awl[gam][ks].q = *(const uint4*)(WhhLo + off);
        }
    float bg[3][4];
    #pragma unroll
    for (int gam = 0; gam < 3; ++gam)
        #pragma unroll
        for (int r = 0; r < 4; ++r)
            bg[gam][r] = bhh[64 * gam + 16 * wt + 4 * g + r];

    // projection A-frags + bias (only when fused proj requested)
    B8u pwh[3][2], pwl[3][2];
    float bg2[3][4];
    if (do_proj) {
        #pragma unroll
        for (int gam = 0; gam < 3; ++gam)
            #pragma unroll
            for (int ks = 0; ks < 2; ++ks) {
                size_t off = (size_t)(64 * gam + 16 * wt + c) * 64 + 32 * ks + 8 * g;
                pwh[gam][ks].q = *(const uint4*)(WIhi + off);
                pwl[gam][ks].q = *(const uint4*)(WIlo + off);
            }
        #pragma unroll
        for (int gam = 0; gam < 3; ++gam)
            #pragma unroll
            for (int r = 0; r < 4; ++r)
                bg2[gam][r] = bih_next[64 * gam + 16 * wt + 4 * g + r];
    }

    {
        ushort* zh = &Hh[0][0][0];
        ushort* zl = &Hl[0][0][0];
        for (int i = tid; i < 2 * 16 * PAD; i += 256) { zh[i] = 0; zl[i] = 0; }
    }
    float hold[4] = {0.f, 0.f, 0.f, 0.f};

    F4u gi[3];
    {
        const float* xp = X + ((size_t)(b0 + c)) * 192;
        #pragma unroll
        for (int gam = 0; gam < 3; ++gam)
            gi[gam].v = *(const float4*)(xp + 64 * gam + 16 * wt + 4 * g);
    }
    __syncthreads();

    for (int t = 0; t < SEQL; ++t) {
        const int p = t & 1;

        B8u bh[2], bl[2];
        #pragma unroll
        for (int ks = 0; ks < 2; ++ks) {
            const int sl = (4 * ks + g) ^ (c & 7);
            bh[ks].q = *(const uint4*)&Hh[p][c][sl * 8];
            bl[ks].q = *(const uint4*)&Hl[p][c][sl * 8];
        }

        // recurrence GH = Whh . h[t-1]
        f32x4 a0[3], a1[3];
        #pragma unroll
        for (int gam = 0; gam < 3; ++gam) {
            a0[gam] = (f32x4){bg[gam][0], bg[gam][1], bg[gam][2], bg[gam][3]};
            a1[gam] = (f32x4){0.f, 0.f, 0.f, 0.f};
        }
        #pragma unroll
        for (int gam = 0; gam < 3; ++gam) {
            a0[gam] = __builtin_amdgcn_mfma_f32_16x16x32_bf16(awh[gam][0].v, bh[0].v, a0[gam], 0, 0, 0);
            a1[gam] = __builtin_amdgcn_mfma_f32_16x16x32_bf16(awh[gam][1].v, bh[1].v, a1[gam], 0, 0, 0);
            a0[gam] = __builtin_amdgcn_mfma_f32_16x16x32_bf16(awl[gam][0].v, bh[0].v, a0[gam], 0, 0, 0);
            a1[gam] = __builtin_amdgcn_mfma_f32_16x16x32_bf16(awl[gam][1].v, bh[1].v, a1[gam], 0, 0, 0);
            a0[gam] = __builtin_amdgcn_mfma_f32_16x16x32_bf16(awh[gam][0].v, bl[0].v, a0[gam], 0, 0, 0);
            a1[gam] = __builtin_amdgcn_mfma_f32_16x16x32_bf16(awh[gam][1].v, bl[1].v, a1[gam], 0, 0, 0);
        }

        // fused projection: gi_next[t-1] = bih + h[t-1] @ Wih.T (same B-frags)
        if (do_proj && t > 0) {
            f32x4 pa[3];
            #pragma unroll
            for (int gam = 0; gam < 3; ++gam)
                pa[gam] = (f32x4){bg2[gam][0], bg2[gam][1], bg2[gam][2], bg2[gam][3]};
            #pragma unroll
            for (int gam = 0; gam < 3; ++gam) {
                pa[gam] = __builtin_amdgcn_mfma_f32_16x16x32_bf16(pwh[gam][0].v, bh[0].v, pa[gam], 0, 0, 0);
                pa[gam] = __builtin_amdgcn_mfma_f32_16x16x32_bf16(pwh[gam][1].v, bh[1].v, pa[gam], 0, 0, 0);
                pa[gam] = __builtin_amdgcn_mfma_f32_16x16x32_bf16(pwl[gam][0].v, bh[0].v, pa[gam], 0, 0, 0);
                pa[gam] = __builtin_amdgcn_mfma_f32_16x16x32_bf16(pwl[gam][1].v, bh[1].v, pa[gam], 0, 0, 0);
                pa[gam] = __builtin_amdgcn_mfma_f32_16x16x32_bf16(pwh[gam][0].v, bl[0].v, pa[gam], 0, 0, 0);
                pa[gam] = __builtin_amdgcn_mfma_f32_16x16x32_bf16(pwh[gam][1].v, bl[1].v, pa[gam], 0, 0, 0);
            }
            const size_t prow = (size_t)(t - 1) * NB + b0 + c;
            #pragma unroll
            for (int gam = 0; gam < 3; ++gam)
                *(float4*)&Xout[prow * 192 + 64 * gam + 16 * wt + 4 * g] =
                    make_float4(pa[gam][0], pa[gam][1], pa[gam][2], pa[gam][3]);
        }

        F4u ngi[3];
        {
            const int tn = (t + 1 < SEQL) ? t + 1 : t;
            const float* xp = X + ((size_t)tn * NB + b0 + c) * 192;
            #pragma unroll
            for (int gam = 0; gam < 3; ++gam)
                ngi[gam].v = *(const float4*)(xp + 64 * gam + 16 * wt + 4 * g);
        }

        float hn4[4];
        #pragma unroll
        for (int r = 0; r < 4; ++r) {
            const float gr = a0[0][r] + a1[0][r];
            const float gz = a0[1][r] + a1[1][r];
            const float gn = a0[2][r] + a1[2][r];
            const float rr = fast_sig(gi[0].f[r] + gr);
            const float zz = fast_sig(gi[1].f[r] + gz);
            const float nn = fast_tanh(gi[2].f[r] + rr * gn);
            hn4[r] = (1.f - zz) * nn + zz * hold[r];
            hold[r] = hn4[r];
        }

        if (Y) {
            const size_t row = out_batch_major ? ((size_t)(b0 + c) * SEQL + t)
                                               : ((size_t)t * NB + b0 + c);
            *(float4*)&Y[row * 64 + 16 * wt + 4 * g] =
                make_float4(hn4[0], hn4[1], hn4[2], hn4[3]);
        }

        {
            ushort hh[4], hl[4];
            #pragma unroll
            for (int r = 0; r < 4; ++r) {
                ushort h = f2bf(hn4[r]);
                hh[r] = h;
                hl[r] = f2bf(hn4[r] - __uint_as_float(((uint)h) << 16));
            }
            const int sl = (2 * wt + (g >> 1)) ^ (c & 7);
            const int ad = sl * 8 + (g & 1) * 4;
            *(uint2*)&Hh[p ^ 1][c][ad] = make_uint2((uint)hh[0] | ((uint)hh[1] << 16),
                                                    (uint)hh[2] | ((uint)hh[3] << 16));
            *(uint2*)&Hl[p ^ 1][c][ad] = make_uint2((uint)hl[0] | ((uint)hl[1] << 16),
                                                    (uint)hl[2] | ((uint)hl[3] << 16));
        }
        #pragma unroll
        for (int gam = 0; gam < 3; ++gam) gi[gam].v = ngi[gam].v;

        asm volatile("s_waitcnt lgkmcnt(0)" ::: "memory");
        __builtin_amdgcn_sched_barrier(0);
        __builtin_amdgcn_s_barrier();
        __builtin_amdgcn_sched_barrier(0);
    }

    // tail: projection of h[SEQL-1] (lives in buffer SEQL&1 after last step)
    if (do_proj) {
        const int p = SEQL & 1;
        B8u bh[2], bl[2];
        #pragma unroll
        for (int ks = 0; ks < 2; ++ks) {
            const int sl = (4 * ks + g) ^ (c & 7);
            bh[ks].q = *(const uint4*)&Hh[p][c][sl * 8];
            bl[ks].q = *(const uint4*)&Hl[p][c][sl * 8];
        }
        f32x4 pa[3];
        #pragma unroll
        for (int gam = 0; gam < 3; ++gam)
            pa[gam] = (f32x4){bg2[gam][0], bg2[gam][1], bg2[gam][2], bg2[gam][3]};
        #pragma unroll
        for (int gam = 0; gam < 3; ++gam) {
            pa[gam] = __builtin_amdgcn_mfma_f32_16x16x32_bf16(pwh[gam][0].v, bh[0].v, pa[gam], 0, 0, 0);
            pa[gam] = __builtin_amdgcn_mfma_f32_16x16x32_bf16(pwh[gam][1].v, bh[1].v, pa[gam], 0, 0, 0);
            pa[gam] = __builtin_amdgcn_mfma_f32_16x16x32_bf16(pwl[gam][0].v, bh[0].v, pa[gam], 0, 0, 0);
            pa[gam] = __builtin_amdgcn_mfma_f32_16x16x32_bf16(pwl[gam][1].v, bh[1].v, pa[gam], 0, 0, 0);
            pa[gam] = __builtin_amdgcn_mfma_f32_16x16x32_bf16(pwh[gam][0].v, bl[0].v, pa[gam], 0, 0, 0);
            pa[gam] = __builtin_amdgcn_mfma_f32_16x16x32_bf16(pwh[gam][1].v, bl[1].v, pa[gam], 0, 0, 0);
        }
        const size_t prow = (size_t)(SEQL - 1) * NB + b0 + c;
        #pragma unroll
        for (int gam = 0; gam < 3; ++gam)
            *(float4*)&Xout[prow * 192 + 64 * gam + 16 * wt + 4 * g] =
                make_float4(pa[gam][0], pa[gam][1], pa[gam][2], pa[gam][3]);
    }
}

// ---------------------------------------------------------------------------
// MFMA GEMM, K=64, fp32 output (QKV projections)
// ---------------------------------------------------------------------------
template<int NCOLS>
__global__ __launch_bounds__(256, 2) void gemm_mfma(
    const float* __restrict__ A, const ushort* __restrict__ Whi,
    const ushort* __restrict__ Wlo, const float* __restrict__ bias,
    float* __restrict__ C)
{
    const int tid = threadIdx.x;
    const int w   = tid >> 6;
    const int lane = tid & 63;
    const int c = lane & 15;
    const int g = lane >> 4;
    const int m0 = blockIdx.x * 128 + 32 * w;

    B8u ah[2][2], al[2][2];
    #pragma unroll
    for (int rm = 0; rm < 2; ++rm) {
        const float* ap = A + (size_t)(m0 + 16 * rm + c) * 64;
        #pragma unroll
        for (int ks = 0; ks < 2; ++ks) {
            float4 v0 = *(const float4*)(ap + 32 * ks + 8 * g);
            float4 v1 = *(const float4*)(ap + 32 * ks + 8 * g + 4);
            split8(v0, v1, ah[rm][ks], al[rm][ks]);
        }
    }

    f32x4 acc[NCOLS / 16][2];
    #pragma unroll
    for (int nt = 0; nt < NCOLS / 16; ++nt) {
        float bv = bias[16 * nt + c];
        #pragma unroll
        for (int rm = 0; rm < 2; ++rm)
            acc[nt][rm] = (f32x4){bv, bv, bv, bv};
    }

    #pragma unroll
    for (int nt = 0; nt < NCOLS / 16; ++nt) {
        B8u wh[2], wl[2];
        #pragma unroll
        for (int ks = 0; ks < 2; ++ks) {
            size_t off = (size_t)(16 * nt + c) * 64 + 32 * ks + 8 * g;
            wh[ks].q = *(const uint4*)(Whi + off);
            wl[ks].q = *(const uint4*)(Wlo + off);
        }
        #pragma unroll
        for (int rm = 0; rm < 2; ++rm)
            #pragma unroll
            for (int ks = 0; ks < 2; ++ks) {
                acc[nt][rm] = __builtin_amdgcn_mfma_f32_16x16x32_bf16(ah[rm][ks].v, wh[ks].v, acc[nt][rm], 0, 0, 0);
                acc[nt][rm] = __builtin_amdgcn_mfma_f32_16x16x32_bf16(al[rm][ks].v, wh[ks].v, acc[nt][rm], 0, 0, 0);
                acc[nt][rm] = __builtin_amdgcn_mfma_f32_16x16x32_bf16(ah[rm][ks].v, wl[ks].v, acc[nt][rm], 0, 0, 0);
            }
    }

    #pragma unroll
    for (int nt = 0; nt < NCOLS / 16; ++nt)
        #pragma unroll
        for (int rm = 0; rm < 2; ++rm)
            #pragma unroll
            for (int reg = 0; reg < 4; ++reg) {
                int row = m0 + 16 * rm + 4 * g + reg;
                C[(size_t)row * NCOLS + 16 * nt + c] = acc[nt][rm][reg];
            }
}

// ---------------------------------------------------------------------------
// FUSED: GEMM (K=64, NCOLS=64) + residual add + LayerNorm.
// ---------------------------------------------------------------------------
__global__ __launch_bounds__(256, 2) void gemm_ln_mfma(
    const float* __restrict__ A, const ushort* __restrict__ Whi,
    const ushort* __restrict__ Wlo, const float* __restrict__ bias,
    const float* __restrict__ resid,
    const float* __restrict__ lns, const float* __restrict__ lnb,
    float* __restrict__ O)
{
    const int tid = threadIdx.x;
    const int w   = tid >> 6;
    const int lane = tid & 63;
    const int c = lane & 15;
    const int g = lane >> 4;
    const int m0 = blockIdx.x * 128 + 32 * w;

    B8u ah[2][2], al[2][2];
    #pragma unroll
    for (int rm = 0; rm < 2; ++rm) {
        const float* ap = A + (size_t)(m0 + 16 * rm + c) * 64;
        #pragma unroll
        for (int ks = 0; ks < 2; ++ks) {
            float4 v0 = *(const float4*)(ap + 32 * ks + 8 * g);
            float4 v1 = *(const float4*)(ap + 32 * ks + 8 * g + 4);
            split8(v0, v1, ah[rm][ks], al[rm][ks]);
        }
    }

    f32x4 acc[4][2];
    #pragma unroll
    for (int nt = 0; nt < 4; ++nt) {
        float bv = bias[16 * nt + c];
        #pragma unroll
        for (int rm = 0; rm < 2; ++rm)
            acc[nt][rm] = (f32x4){bv, bv, bv, bv};
    }

    #pragma unroll
    for (int nt = 0; nt < 4; ++nt) {
        B8u wh[2], wl[2];
        #pragma unroll
        for (int ks = 0; ks < 2; ++ks) {
            size_t off = (size_t)(16 * nt + c) * 64 + 32 * ks + 8 * g;
            wh[ks].q = *(const uint4*)(Whi + off);
            wl[ks].q = *(const uint4*)(Wlo + off);
        }
        #pragma unroll
        for (int rm = 0; rm < 2; ++rm)
            #pragma unroll
            for (int ks = 0; ks < 2; ++ks) {
                acc[nt][rm] = __builtin_amdgcn_mfma_f32_16x16x32_bf16(ah[rm][ks].v, wh[ks].v, acc[nt][rm], 0, 0, 0);
                acc[nt][rm] = __builtin_amdgcn_mfma_f32_16x16x32_bf16(al[rm][ks].v, wh[ks].v, acc[nt][rm], 0, 0, 0);
                acc[nt][rm] = __builtin_amdgcn_mfma_f32_16x16x32_bf16(ah[rm][ks].v, wl[ks].v, acc[nt][rm], 0, 0, 0);
            }
    }

    float vv[4][2][4];
    #pragma unroll
    for (int nt = 0; nt < 4; ++nt)
        #pragma unroll
        for (int rm = 0; rm < 2; ++rm)
            #pragma unroll
            for (int reg = 0; reg < 4; ++reg) {
                const int row = m0 + 16 * rm + 4 * g + reg;
                const float a = acc[nt][rm][reg];
                const float r_ = resid ? resid[(size_t)row * 64 + 16 * nt + c] : a;
                vv[nt][rm][reg] = a + r_;
            }

    float sv[4], bv[4];
    #pragma unroll
    for (int nt = 0; nt < 4; ++nt) { sv[nt] = lns[16 * nt + c]; bv[nt] = lnb[16 * nt + c]; }

    #pragma unroll
    for (int rm = 0; rm < 2; ++rm)
        #pragma unroll
        for (int reg = 0; reg < 4; ++reg) {
            float sum = vv[0][rm][reg] + vv[1][rm][reg] + vv[2][rm][reg] + vv[3][rm][reg];
            float sq  = vv[0][rm][reg]*vv[0][rm][reg] + vv[1][rm][reg]*vv[1][rm][reg]
                      + vv[2][rm][reg]*vv[2][rm][reg] + vv[3][rm][reg]*vv[3][rm][reg];
            #pragma unroll
            for (int off = 1; off < 16; off <<= 1) {
                sum += __shfl_xor(sum, off);
                sq  += __shfl_xor(sq,  off);
            }
            const float mean = sum * (1.f / 64.f);
            const float var  = sq * (1.f / 64.f) - mean * mean;
            const float inv  = rsqrtf(var + 1e-5f);
            const int row = m0 + 16 * rm + 4 * g + reg;
            #pragma unroll
            for (int nt = 0; nt < 4; ++nt)
                O[(size_t)row * 64 + 16 * nt + c] =
                    (vv[nt][rm][reg] - mean) * inv * sv[nt] + bv[nt];
        }
}

// ---------------------------------------------------------------------------
// FUSED: FFN + residual + LayerNorm.
// ---------------------------------------------------------------------------
__global__ __launch_bounds__(256, 2) void ffn_ln_mfma(
    const float* __restrict__ Xin,
    const ushort* __restrict__ W1hi, const ushort* __restrict__ W1lo,
    const ushort* __restrict__ W2hi, const ushort* __restrict__ W2lo,
    const float* __restrict__ b1, const float* __restrict__ b2,
    const float* __restrict__ lns, const float* __restrict__ lnb,
    float* __restrict__ Out)
{
    __shared__ __align__(16) ushort sW1h[64 * 72], sW1l[64 * 72];
    __shared__ __align__(16) ushort sW2h[64 * 72], sW2l[64 * 72];
    __shared__ __align__(16) ushort sHh[128 * 72], sHl[128 * 72];
    __shared__ float sb1[64];

    const int tid = threadIdx.x;
    const int w   = tid >> 6;
    const int lane = tid & 63;
    const int c = lane & 15;
    const int g = lane >> 4;
    const int r0 = blockIdx.x * 128;

    B8u xh[2][2], xl[2][2];
    #pragma unroll
    for (int rm = 0; rm < 2; ++rm) {
        const float* ap = Xin + (size_t)(r0 + 32 * w + 16 * rm + c) * 64;
        #pragma unroll
        for (int ks = 0; ks < 2; ++ks) {
            float4 v0 = *(const float4*)(ap + 32 * ks + 8 * g);
            float4 v1 = *(const float4*)(ap + 32 * ks + 8 * g + 4);
            split8(v0, v1, xh[rm][ks], xl[rm][ks]);
        }
    }

    f32x4 acc2[4][2];
    #pragma unroll
    for (int jt = 0; jt < 4; ++jt) {
        float bv = b2[16 * jt + c];
        #pragma unroll
        for (int mt = 0; mt < 2; ++mt)
            acc2[jt][mt] = (f32x4){bv, bv, bv, bv};
    }

    for (int nc = 0; nc < 16; ++nc) {
        __syncthreads();
        {
            const int n = tid >> 2, s = tid & 3;
            size_t s1 = (size_t)(nc * 64 + n) * 64 + s * 16;
            size_t s2 = (size_t)n * 1024 + nc * 64 + s * 16;
            int d = n * 72 + s * 16;
            *(uint4*)&sW1h[d]     = *(const uint4*)(W1hi + s1);
            *(uint4*)&sW1h[d + 8] = *(const uint4*)(W1hi + s1 + 8);
            *(uint4*)&sW1l[d]     = *(const uint4*)(W1lo + s1);
            *(uint4*)&sW1l[d + 8] = *(const uint4*)(W1lo + s1 + 8);
            *(uint4*)&sW2h[d]     = *(const uint4*)(W2hi + s2);
            *(uint4*)&sW2h[d + 8] = *(const uint4*)(W2hi + s2 + 8);
            *(uint4*)&sW2l[d]     = *(const uint4*)(W2lo + s2);
            *(uint4*)&sW2l[d + 8] = *(const uint4*)(W2lo + s2 + 8);
            if (tid < 64) sb1[tid] = b1[nc * 64 + tid];
        }
        __syncthreads();

        f32x4 acc1[4][2];
        #pragma unroll
        for (int jm = 0; jm < 4; ++jm) {
            float b0 = sb1[16 * jm + 4 * g + 0];
            float b1v = sb1[16 * jm + 4 * g + 1];
            float b2v = sb1[16 * jm + 4 * g + 2];
            float b3v = sb1[16 * jm + 4 * g + 3];
            #pragma unroll
            for (int rm = 0; rm < 2; ++rm)
                acc1[jm][rm] = (f32x4){b0, b1v, b2v, b3v};
        }
        #pragma unroll
        for (int jm = 0; jm < 4; ++jm) {
            B8u w1h[2], w1l[2];
            #pragma unroll
            for (int ks = 0; ks < 2; ++ks) {
                int off = (16 * jm + c) * 72 + 32 * ks + 8 * g;
                w1h[ks].q = *(const uint4*)&sW1h[off];
                w1l[ks].q = *(const uint4*)&sW1l[off];
            }
            #pragma unroll
            for (int rm = 0; rm < 2; ++rm)
                #pragma unroll
                for (int ks = 0; ks < 2; ++ks) {
                    acc1[jm][rm] = __builtin_amdgcn_mfma_f32_16x16x32_bf16(w1h[ks].v, xh[rm][ks].v, acc1[jm][rm], 0, 0, 0);
                    acc1[jm][rm] = __builtin_amdgcn_mfma_f32_16x16x32_bf16(w1l[ks].v, xh[rm][ks].v, acc1[jm][rm], 0, 0, 0);
                    acc1[jm][rm] = __builtin_amdgcn_mfma_f32_16x16x32_bf16(w1h[ks].v, xl[rm][ks].v, acc1[jm][rm], 0, 0, 0);
                }
        }
        #pragma unroll
        for (int jm = 0; jm < 4; ++jm)
            #pragma unroll
            for (int rm = 0; rm < 2; ++rm) {
                ushort hh[4], hl[4];
                #pragma unroll
                for (int reg = 0; reg < 4; ++reg) {
                    float hv = fmaxf(acc1[jm][rm][reg], 0.f);
                    ushort h = f2bf(hv);
                    hh[reg] = h;
                    float fh = __uint_as_float(((uint)h) << 16);
                    hl[reg] = f2bf(hv - fh);
                }
                int el = (32 * w + 16 * rm + c) * 72 + 16 * jm + 4 * g;
                *(uint2*)&sHh[el] = make_uint2((uint)hh[0] | ((uint)hh[1] << 16),
                                               (uint)hh[2] | ((uint)hh[3] << 16));
                *(uint2*)&sHl[el] = make_uint2((uint)hl[0] | ((uint)hl[1] << 16),
                                               (uint)hl[2] | ((uint)hl[3] << 16));
            }
        asm volatile("s_waitcnt lgkmcnt(0)" ::: "memory");
        __builtin_amdgcn_sched_barrier(0);

        #pragma unroll
        for (int ks = 0; ks < 2; ++ks) {
            B8u ahh[2], ahl[2], bwh[4], bwl[4];
            #pragma unroll
            for (int mt = 0; mt < 2; ++mt) {
                int el = (32 * w + 16 * mt + c) * 72 + 32 * ks + 8 * g;
                ahh[mt].q = *(const uint4*)&sHh[el];
                ahl[mt].q = *(const uint4*)&sHl[el];
            }
            #pragma unroll
            for (int jt = 0; jt < 4; ++jt) {
                int el = (16 * jt + c) * 72 + 32 * ks + 8 * g;
                bwh[jt].q = *(const uint4*)&sW2h[el];
                bwl[jt].q = *(const uint4*)&sW2l[el];
            }
            #pragma unroll
            for (int jt = 0; jt < 4; ++jt)
                #pragma unroll
                for (int mt = 0; mt < 2; ++mt) {
                    acc2[jt][mt] = __builtin_amdgcn_mfma_f32_16x16x32_bf16(ahh[mt].v, bwh[jt].v, acc2[jt][mt], 0, 0, 0);
                    acc2[jt][mt] = __builtin_amdgcn_mfma_f32_16x16x32_bf16(ahl[mt].v, bwh[jt].v, acc2[jt][mt], 0, 0, 0);
                    acc2[jt][mt] = __builtin_amdgcn_mfma_f32_16x16x32_bf16(ahh[mt].v, bwl[jt].v, acc2[jt][mt], 0, 0, 0);
                }
        }
    }

    float vv[4][2][4];
    #pragma unroll
    for (int jt = 0; jt < 4; ++jt)
        #pragma unroll
        for (int mt = 0; mt < 2; ++mt)
            #pragma unroll
            for (int reg = 0; reg < 4; ++reg) {
                const int row = r0 + 32 * w + 16 * mt + 4 * g + reg;
                vv[jt][mt][reg] = fmaxf(acc2[jt][mt][reg], 0.f) +
                                  Xin[(size_t)row * 64 + 16 * jt + c];
            }

    float sv[4], bv[4];
    #pragma unroll
    for (int jt = 0; jt < 4; ++jt) { sv[jt] = lns[16 * jt + c]; bv[jt] = lnb[16 * jt + c]; }

    #pragma unroll
    for (int mt = 0; mt < 2; ++mt)
        #pragma unroll
        for (int reg = 0; reg < 4; ++reg) {
            float sum = vv[0][mt][reg] + vv[1][mt][reg] + vv[2][mt][reg] + vv[3][mt][reg];
            float sq  = vv[0][mt][reg]*vv[0][mt][reg] + vv[1][mt][reg]*vv[1][mt][reg]
                      + vv[2][mt][reg]*vv[2][mt][reg] + vv[3][mt][reg]*vv[3][mt][reg];
            #pragma unroll
            for (int off = 1; off < 16; off <<= 1) {
                sum += __shfl_xor(sum, off);
                sq  += __shfl_xor(sq,  off);
            }
            const float mean = sum * (1.f / 64.f);
            const float var  = sq * (1.f / 64.f) - mean * mean;
            const float inv  = rsqrtf(var + 1e-5f);
            const int row = r0 + 32 * w + 16 * mt + 4 * g + reg;
            #pragma unroll
            for (int jt = 0; jt < 4; ++jt)
                Out[(size_t)row * 64 + 16 * jt + c] =
                    (vv[jt][mt][reg] - mean) * inv * sv[jt] + bv[jt];
        }
}

// ---------------------------------------------------------------------------
// MFMA flash attention (r13 version: fp32 QKV, split in-kernel)
// ---------------------------------------------------------------------------
__global__ __launch_bounds__(256, 2) void attn_mfma(
    const float* __restrict__ QKV, float* __restrict__ Out)
{
    __shared__ __align__(16) ushort Ph[4][4096];
    __shared__ __align__(16) ushort Pl[4][4096];

    const int h = blockIdx.x;
    const int b = blockIdx.y;
    const int tid = threadIdx.x;
    const int w = tid >> 6;
    const int lane = tid & 63;
    const int c = lane & 15;
    const int g = lane >> 4;
    const float scale = 0.17677669529663687f; // 1/sqrt(32)

    const float* base = QKV + (size_t)b * SEQL * 192;
    ushort* phw = Ph[w];
    ushort* plw = Pl[w];

    B8u qh[4], ql[4];
    #pragma unroll
    for (int qt = 0; qt < 4; ++qt) {
        const float* p = base + (size_t)(64 * w + 16 * qt + c) * 192 + h * 32 + 8 * g;
        float4 v0 = *(const float4*)p;
        float4 v1 = *(const float4*)(p + 4);
        v0.x *= scale; v0.y *= scale; v0.z *= scale; v0.w *= scale;
        v1.x *= scale; v1.y *= scale; v1.z *= scale; v1.w *= scale;
        split8(v0, v1, qh[qt], ql[qt]);
    }

    f32x4 o[2][4];
    #pragma unroll
    for (int dt = 0; dt < 2; ++dt)
        #pragma unroll
        for (int qt = 0; qt < 4; ++qt)
            o[dt][qt] = (f32x4){0.f, 0.f, 0.f, 0.f};
    float mrun[4] = {-1e30f, -1e30f, -1e30f, -1e30f};
    float lrun[4] = {0.f, 0.f, 0.f, 0.f};

    for (int kc = 0; kc < 4; ++kc) {
        B8u kh[4], kl[4];
        #pragma unroll
        for (int kt = 0; kt < 4; ++kt) {
            const float* p = base + (size_t)(kc * 64 + 16 * kt + c) * 192 + 64 + h * 32 + 8 * g;
            split8(*(const float4*)p, *(const float4*)(p + 4), kh[kt], kl[kt]);
        }
        f32x4 st[4][4];
        #pragma unroll
        for (int kt = 0; kt < 4; ++kt)
            #pragma unroll
            for (int qt = 0; qt < 4; ++qt)
                st[kt][qt] = (f32x4){0.f, 0.f, 0.f, 0.f};
        #pragma unroll
        for (int kt = 0; kt < 4; ++kt)
            #pragma unroll
            for (int qt = 0; qt < 4; ++qt) {
                st[kt][qt] = __builtin_amdgcn_mfma_f32_16x16x32_bf16(kh[kt].v, qh[qt].v, st[kt][qt], 0, 0, 0);
                st[kt][qt] = __builtin_amdgcn_mfma_f32_16x16x32_bf16(kl[kt].v, qh[qt].v, st[kt][qt], 0, 0, 0);
                st[kt][qt] = __builtin_amdgcn_mfma_f32_16x16x32_bf16(kh[kt].v, ql[qt].v, st[kt][qt], 0, 0, 0);
            }

        asm volatile("s_waitcnt lgkmcnt(0)" ::: "memory");
        #pragma unroll
        for (int qt = 0; qt < 4; ++qt) {
            float cmax = st[0][qt][0];
            #pragma unroll
            for (int kt = 0; kt < 4; ++kt)
                #pragma unroll
                for (int r = 0; r < 4; ++r) cmax = fmaxf(cmax, st[kt][qt][r]);
            cmax = fmaxf(cmax, __shfl_xor(cmax, 16));
            cmax = fmaxf(cmax, __shfl_xor(cmax, 32));
            const float mnew = fmaxf(mrun[qt], cmax);
            const float corr = __expf(mrun[qt] - mnew);
            mrun[qt] = mnew;
            const int ql_ = 16 * qt + c;
            float csum = 0.f;
            #pragma unroll
            for (int kt = 0; kt < 4; ++kt) {
                ushort hh[4], hl[4];
                #pragma unroll
                for (int r = 0; r < 4; ++r) {
                    float pv = __expf(st[kt][qt][r] - mnew);
                    csum += pv;
                    ushort ph_ = f2bf(pv);
                    hh[r] = ph_;
                    hl[r] = f2bf(pv - __uint_as_float(((uint)ph_) << 16));
                }
                const int ow = (2 * kt + (g >> 1)) ^ (ql_ & 7);
                const int addr = ql_ * 64 + ow * 8 + (g & 1) * 4;
                *(uint2*)&phw[addr] = make_uint2((uint)hh[0] | ((uint)hh[1] << 16),
                                                 (uint)hh[2] | ((uint)hh[3] << 16));
                *(uint2*)&plw[addr] = make_uint2((uint)hl[0] | ((uint)hl[1] << 16),
                                                 (uint)hl[2] | ((uint)hl[3] << 16));
            }
            csum += __shfl_xor(csum, 16);
            csum += __shfl_xor(csum, 32);
            lrun[qt] = lrun[qt] * corr + csum;
            #pragma unroll
            for (int dt = 0; dt < 2; ++dt)
                #pragma unroll
                for (int r = 0; r < 4; ++r) o[dt][qt][r] *= corr;
        }

        B8u vh[2][2], vl[2][2];
        #pragma unroll
        for (int ks = 0; ks < 2; ++ks)
            #pragma unroll
            for (int dt = 0; dt < 2; ++dt) {
                const float* vp = base + (size_t)(kc * 64 + ks * 32 + 8 * g) * 192 + 128 + h * 32 + 16 * dt + c;
                float f0 = vp[0], f1 = vp[192], f2 = vp[384], f3 = vp[576];
                float f4 = vp[768], f5 = vp[960], f6 = vp[1152], f7 = vp[1344];
                split8(make_float4(f0, f1, f2, f3), make_float4(f4, f5, f6, f7),
                       vh[ks][dt], vl[ks][dt]);
            }

        asm volatile("s_waitcnt lgkmcnt(0)" ::: "memory");
        __builtin_amdgcn_sched_barrier(0);

        #pragma unroll
        for (int ks = 0; ks < 2; ++ks)
            #pragma unroll
            for (int qt = 0; qt < 4; ++qt) {
                const int ql_ = 16 * qt + c;
                const int orr = (ks * 4 + g) ^ (ql_ & 7);
                const int addr = ql_ * 64 + orr * 8;
                B8u pbh, pbl;
                pbh.q = *(const uint4*)&phw[addr];
                pbl.q = *(const uint4*)&plw[addr];
                #pragma unroll
                for (int dt = 0; dt < 2; ++dt) {
                    o[dt][qt] = __builtin_amdgcn_mfma_f32_16x16x32_bf16(vh[ks][dt].v, pbh.v, o[dt][qt], 0, 0, 0);
                    o[dt][qt] = __builtin_amdgcn_mfma_f32_16x16x32_bf16(vl[ks][dt].v, pbh.v, o[dt][qt], 0, 0, 0);
                    o[dt][qt] = __builtin_amdgcn_mfma_f32_16x16x32_bf16(vh[ks][dt].v, pbl.v, o[dt][qt], 0, 0, 0);
                }
            }
    }

    #pragma unroll
    for (int qt = 0; qt < 4; ++qt) {
        const float inv = 1.f / lrun[qt];
        const size_t row = (size_t)b * SEQL + 64 * w + 16 * qt + c;
        #pragma unroll
        for (int dt = 0; dt < 2; ++dt)
            #pragma unroll
            for (int r = 0; r < 4; ++r)
                Out[row * 64 + h * 32 + 16 * dt + 4 * g + r] = o[dt][qt][r] * inv;
    }
}

// ---------------------------------------------------------------------------
// Head MLP over last timestep: 64 ->256 ->64 ->32 ->1 (silu x3)
// ---------------------------------------------------------------------------
__global__ __launch_bounds__(256) void head_kernel(
    const float* __restrict__ Hf,
    const float* __restrict__ fw1, const float* __restrict__ fb1,
    const float* __restrict__ fw2, const float* __restrict__ fb2,
    const float* __restrict__ fw3, const float* __restrict__ fb3,
    const float* __restrict__ fw4, const float* __restrict__ fb4,
    float* __restrict__ out)
{
    const int b = blockIdx.x;
    const int tid = threadIdx.x;
    __shared__ float t0[64], t1[256], t2[64], t3[32];
    if (tid < 64) t0[tid] = Hf[((size_t)b * SEQL + (SEQL - 1)) * 64 + tid];
    __syncthreads();
    {
        float acc = fb1[tid];
        #pragma unroll 4
        for (int k = 0; k < 64; ++k) acc += t0[k] * fw1[tid * 64 + k];
        t1[tid] = acc / (1.f + __expf(-acc));
    }
    __syncthreads();
    if (tid < 64) {
        float acc = fb2[tid];
        #pragma unroll 4
        for (int k = 0; k < 256; ++k) acc += t1[k] * fw2[tid * 256 + k];
        t2[tid] = acc / (1.f + __expf(-acc));
    }
    __syncthreads();
    if (tid < 32) {
        float acc = fb3[tid];
        #pragma unroll 4
        for (int k = 0; k < 64; ++k) acc += t2[k] * fw3[tid * 64 + k];
        t3[tid] = acc / (1.f + __expf(-acc));
    }
    __syncthreads();
    if (tid == 0) {
        float acc = fb4[0];
        #pragma unroll
        for (int k = 0; k < 32; ++k) acc += t3[k] * fw4[k];
        out[b] = acc;
    }
}

// ---------------------------------------------------------------------------
extern "C" void kernel_launch(void* const* d_in, const int* in_sizes, int n_in,
                              void* d_out, int out_size, void* d_ws, size_t ws_size,
                              hipStream_t stream) {
    const float* x     = (const float*)d_in[0];
    const float* emb   = (const float*)d_in[1];
    const float* wih0  = (const float*)d_in[2];
    const float* whh0  = (const float*)d_in[3];
    const float* bih0  = (const float*)d_in[4];
    const float* bhh0  = (const float*)d_in[5];
    const float* wih12 = (const float*)d_in[6];
    const float* whh12 = (const float*)d_in[7];
    const float* bih12 = (const float*)d_in[8];
    const float* bhh12 = (const float*)d_in[9];
    const float* in_w1 = (const float*)d_in[10];
    const float* in_b1 = (const float*)d_in[11];
    const float* out_w1= (const float*)d_in[12];
    const float* out_b1= (const float*)d_in[13];
    const float* in_w2 = (const float*)d_in[14];
    const float* in_b2 = (const float*)d_in[15];
    const float* out_w2= (const float*)d_in[16];
    const float* out_b2= (const float*)d_in[17];
    const float* ff_w1 = (const float*)d_in[18];
    const float* ff_b1 = (const float*)d_in[19];
    const float* ff_w2 = (const float*)d_in[20];
    const float* ff_b2 = (const float*)d_in[21];
    const float* ln1_s = (const float*)d_in[22];
    const float* ln1_b = (const float*)d_in[23];
    const float* ln2_s = (const float*)d_in[24];
    const float* ln2_b = (const float*)d_in[25];
    const float* ln3_s = (const float*)d_in[26];
    const float* ln3_b = (const float*)d_in[27];
    const float* ln4_s = (const float*)d_in[28];
    const float* ln4_b = (const float*)d_in[29];
    const float* fw1   = (const float*)d_in[30];
    const float* fb1   = (const float*)d_in[31];
    const float* fw2   = (const float*)d_in[32];
    const float* fb2   = (const float*)d_in[33];
    const float* fw3   = (const float*)d_in[34];
    const float* fb3   = (const float*)d_in[35];
    const float* fw4   = (const float*)d_in[36];
    const float* fb4   = (const float*)d_in[37];

    float* ws = (float*)d_ws;
    float* X  = ws;                       // 98304*192 fp32
    float* S0 = X  + (size_t)NROWS * 192; // 98304*64
    float* S1 = S0 + (size_t)NROWS * 64;
    float* S2 = S1 + (size_t)NROWS * 64;
    // gi buffers for the fused-proj GRU chain:
    //   gi0 = X ; gi1 = [S0 S1 S2] (exactly NROWS*192 fp32) ; gi2 = X (dead)
    //   final h -> S0 (gi1 region, dead by then)
    float* Xmid = S0;

    ushort* bf = (ushort*)(S2 + (size_t)NROWS * 64);
    ushort* ffw1hi = bf;               // 65536
    ushort* ffw1lo = ffw1hi + 65536;
    ushort* ffw2hi = ffw1lo + 65536;   // 65536
    ushort* ffw2lo = ffw2hi + 65536;
    ushort* wghi   = ffw2lo + 65536;   // 24576 (wih12: 2 layers x 192 x 64)
    ushort* wglo   = wghi + 24576;
    ushort* q1hi   = wglo + 24576;     // 12288
    ushort* q1lo   = q1hi + 12288;
    ushort* q2hi   = q1lo + 12288;
    ushort* q2lo   = q2hi + 12288;
    ushort* o1hi   = q2lo + 12288;     // 4096
    ushort* o1lo   = o1hi + 4096;
    ushort* o2hi   = o1lo + 4096;
    ushort* o2lo   = o2hi + 4096;
    ushort* w0hi   = o2lo + 4096;      // whh0: 12288
    ushort* w0lo   = w0hi + 12288;
    ushort* w12hi  = w0lo + 12288;     // whh12: 24576 (2 layers)
    ushort* w12lo  = w12hi + 24576;

    // ---- all weight splits in one launch ----
    split_all<<<880, 256, 0, stream>>>(
        ff_w1, ff_w2, wih12, in_w1, in_w2, out_w1, out_w2, whh0, whh12,
        ffw1hi, ffw2hi, wghi, q1hi, q2hi, o1hi, o2hi, w0hi, w12hi,
        ffw1lo, ffw2lo, wglo, q1lo, q2lo, o1lo, o2lo, w0lo, w12lo);

    // ---- GRU stack with fused inter-layer projections ----
    featproj_kernel<<<NROWS / 32, 192, 0, stream>>>(x, emb, wih0, bih0, X);
    // layer 0: reads gi0=X, emits gi1 -> Xmid (no h store)
    gru_mfma<<<NB / 16, 256, 0, stream>>>(X, w0hi, w0lo, bhh0,
                                          nullptr, 0,
                                          wghi, wglo, bih12, Xmid, 1);
    // layer 1: reads gi1=Xmid, emits gi2 -> X (no h store)
    gru_mfma<<<NB / 16, 256, 0, stream>>>(Xmid, w12hi, w12lo, bhh12,
                                          nullptr, 0,
                                          wghi + 12288, wglo + 12288,
                                          bih12 + 192, X, 1);
    // layer 2: reads gi2=X, writes h (batch-major) -> S0; no proj
    gru_mfma<<<NB / 16, 256, 0, stream>>>(X, w12hi + 12288, w12lo + 12288,
                                          bhh12 + 192, S0, 1,
                                          nullptr, nullptr, nullptr, nullptr, 0);

    // ---- Transformer block 1 ----
    gemm_mfma<192><<<NROWS / 128, 256, 0, stream>>>(S0, q1hi, q1lo, in_b1, X);
    attn_mfma<<<dim3(2, NB), 256, 0, stream>>>(X, S1);
    gemm_ln_mfma<<<NROWS / 128, 256, 0, stream>>>(S1, o1hi, o1lo, out_b1,
                                                  S0, ln1_s, ln1_b, S2);     // h = LN(g + a)
    ffn_ln_mfma<<<NROWS / 128, 256, 0, stream>>>(S2, ffw1hi, ffw1lo, ffw2hi, ffw2lo,
                                                 ff_b1, ff_b2, ln2_s, ln2_b, S0); // h = LN(h+ffn)

    // ---- Transformer block 2 ----
    gemm_mfma<192><<<NROWS / 128, 256, 0, stream>>>(S0, q2hi, q2lo, in_b2, X);
    attn_mfma<<<dim3(2, NB), 256, 0, stream>>>(X, S1);
    gemm_ln_mfma<<<NROWS / 128, 256, 0, stream>>>(S1, o2hi, o2lo, out_b2,
                                                  nullptr, ln3_s, ln3_b, S2); // h = LN(a + a)
    ffn_ln_mfma<<<NROWS / 128, 256, 0, stream>>>(S2, ffw1hi, ffw1lo, ffw2hi, ffw2lo,
                                                 ff_b1, ff_b2, ln4_s, ln4_b, S1); // h = LN(h+ffn)

    // ---- Head ----
    head_kernel<<<NB, 256, 0, stream>>>(S1, fw1, fb1, fw2, fb2, fw3, fb3, fw4, fb4,
                                        (float*)d_out);
    (void)in_sizes; (void)n_in; (void)out_size; (void)ws_size;
}

// Round 17
// 1052.797 us; speedup vs baseline: 1.3137x; 1.3137x over previous
//
#include <hip/hip_runtime.h>

static constexpr int NB   = 384;
static constexpr int SEQL = 256;
static constexpr int NROWS = NB * SEQL; // 98304

typedef short bf16x8 __attribute__((ext_vector_type(8)));
typedef float f32x4  __attribute__((ext_vector_type(4)));

union B8u {
    bf16x8 v;
    ushort us[8];
    uint4  q;
};

union F4u { float4 v; float f[4]; };

__device__ inline ushort f2bf(float f) {
    uint u = __float_as_uint(f);
    uint r = u + 0x7FFFu + ((u >> 16) & 1u);
    return (ushort)(r >> 16);
}

__device__ inline void split8(float4 a, float4 b, B8u& hi, B8u& lo) {
    float f[8] = {a.x, a.y, a.z, a.w, b.x, b.y, b.z, b.w};
    #pragma unroll
    for (int i = 0; i < 8; ++i) {
        ushort h = f2bf(f[i]);
        hi.us[i] = h;
        float fh = __uint_as_float(((uint)h) << 16);
        lo.us[i] = f2bf(f[i] - fh);
    }
}

__device__ inline float fast_rcp(float x) {
    float r = __builtin_amdgcn_rcpf(x);
    return r * (2.f - x * r);
}
__device__ inline float fast_sig(float x) {
    float e = __expf(fminf(-x, 80.f));
    return fast_rcp(1.f + e);
}
__device__ inline float fast_tanh(float a) {
    float e = __expf(fminf(2.f * fabsf(a), 80.f));
    float t = 1.f - 2.f * fast_rcp(1.f + e);
    return (a >= 0.f) ? t : -t;
}

__device__ inline void split1(const float* s, ushort* h, ushort* l, int i) {
    float f = s[i];
    ushort hh = f2bf(f);
    h[i] = hh;
    l[i] = f2bf(f - __uint_as_float(((uint)hh) << 16));
}

// ---------------------------------------------------------------------------
// MERGED: all 9 weight splits (blocks 0..879) + featurize/proj0 (blocks
// 880..3951). Independent work in one launch -> one less dispatch gap.
// ---------------------------------------------------------------------------
__global__ __launch_bounds__(256) void prep_kernel(
    // split sources
    const float* s0, const float* s1, const float* s2, const float* s3,
    const float* s4, const float* s5, const float* s6, const float* s7,
    const float* s8,
    ushort* h0, ushort* h1, ushort* h2, ushort* h3, ushort* h4,
    ushort* h5, ushort* h6, ushort* h7, ushort* h8,
    ushort* l0, ushort* l1, ushort* l2, ushort* l3, ushort* l4,
    ushort* l5, ushort* l6, ushort* l7, ushort* l8,
    // featproj args
    const float* __restrict__ x, const float* __restrict__ emb,
    const float* __restrict__ wih0, const float* __restrict__ bih0,
    float* __restrict__ X)
{
    const int b = blockIdx.x;
    if (b < 880) {
        const float* s; ushort* h; ushort* l; int base;
        if      (b < 256) { s = s0; h = h0; l = l0; base = 0; }
        else if (b < 512) { s = s1; h = h1; l = l1; base = 256; }
        else if (b < 608) { s = s2; h = h2; l = l2; base = 512; }
        else if (b < 656) { s = s3; h = h3; l = l3; base = 608; }
        else if (b < 704) { s = s4; h = h4; l = l4; base = 656; }
        else if (b < 720) { s = s5; h = h5; l = l5; base = 704; }
        else if (b < 736) { s = s6; h = h6; l = l6; base = 720; }
        else if (b < 784) { s = s7; h = h7; l = l7; base = 736; }
        else              { s = s8; h = h8; l = l8; base = 784; }
        split1(s, h, l, (b - base) * 256 + threadIdx.x);
        return;
    }

    // ---- featproj body (tid 0..191 active) ----
    __shared__ float F[32][33];
    const int tid = threadIdx.x;
    const int m0  = (b - 880) * 32;

    if (tid < 96) {
        const int r   = tid & 31;
        const int grp = tid >> 5;
        const int m   = m0 + r;
        const int bb  = m % NB;
        const int l   = m / NB;
        const float* xb = x + (size_t)bb * (3 * SEQL);
        const float x0 = xb[l], x1 = xb[SEQL + l], x2 = xb[2 * SEQL + l];
        const bool is_angle = (bb % 3) == 2;
        float o[10];
        if (is_angle) {
            if (grp < 2) {
                const float a = (grp == 0) ? x0 : x1;
                #pragma unroll
                for (int c = 0; c < 10; ++c) { float d = (float)(c + 1) - a; o[c] = __expf(-d * d); }
            } else {
                float t0 = 1.f, t1 = x2;
                o[0] = 1.f; o[1] = x2;
                #pragma unroll
                for (int c = 2; c < 10; ++c) { float t = 2.f * x2 * t1 - t0; o[c] = t; t0 = t1; t1 = t; }
            }
        } else {
            if (grp < 2) {
                const float xv = (grp == 0) ? x0 : x1;
                int idx = (int)xv; idx = idx < 0 ? 0 : (idx > 118 ? 118 : idx);
                #pragma unroll
                for (int c = 0; c < 10; ++c) o[c] = emb[idx * 10 + c];
            } else {
                #pragma unroll
                for (int c = 0; c < 10; ++c) { float d = (float)(c + 1) - x2; o[c] = __expf(-d * d); }
            }
        }
        #pragma unroll
        for (int c = 0; c < 10; ++c) F[r][grp * 10 + c] = o[c];
    }
    __syncthreads();

    if (tid < 192) {
        float w[30];
        #pragma unroll
        for (int k = 0; k < 30; ++k) w[k] = wih0[tid * 30 + k];
        const float bj = bih0[tid];
        for (int r = 0; r < 32; ++r) {
            float acc = bj;
            #pragma unroll
            for (int k = 0; k < 30; ++k) acc += F[r][k] * w[k];
            X[(size_t)(m0 + r) * 192 + tid] = acc;
        }
    }
}

// ---------------------------------------------------------------------------
// GRU recurrence (r13 config, proven 190 us): MFMA, cheap activations,
// lgkm-only barrier. 16 batch rows/block, 4 waves.
// ---------------------------------------------------------------------------
__global__ __launch_bounds__(256, 1) void gru_mfma(
    const float* __restrict__ X, const ushort* __restrict__ WhhHi,
    const ushort* __restrict__ WhhLo, const float* __restrict__ bhh,
    float* __restrict__ Y, int out_batch_major)
{
    constexpr int PAD = 88;
    __shared__ __align__(16) ushort Hh[2][16][PAD];
    __shared__ __align__(16) ushort Hl[2][16][PAD];

    const int tid  = threadIdx.x;
    const int wt   = tid >> 6;
    const int lane = tid & 63;
    const int c    = lane & 15;
    const int g    = lane >> 4;
    const int b0   = blockIdx.x * 16;

    B8u awh[3][2], awl[3][2];
    #pragma unroll
    for (int gam = 0; gam < 3; ++gam)
        #pragma unroll
        for (int ks = 0; ks < 2; ++ks) {
            size_t off = (size_t)(64 * gam + 16 * wt + c) * 64 + 32 * ks + 8 * g;
            awh[gam][ks].q = *(const uint4*)(WhhHi + off);
            awl[gam][ks].q = *(const uint4*)(WhhLo + off);
        }
    float bg[3][4];
    #pragma unroll
    for (int gam = 0; gam < 3; ++gam)
        #pragma unroll
        for (int r = 0; r < 4; ++r)
            bg[gam][r] = bhh[64 * gam + 16 * wt + 4 * g + r];

    {
        ushort* zh = &Hh[0][0][0];
        ushort* zl = &Hl[0][0][0];
        for (int i = tid; i < 2 * 16 * PAD; i += 256) { zh[i] = 0; zl[i] = 0; }
    }
    float hold[4] = {0.f, 0.f, 0.f, 0.f};

    F4u gi[3];
    {
        const float* xp = X + ((size_t)(b0 + c)) * 192;
        #pragma unroll
        for (int gam = 0; gam < 3; ++gam)
            gi[gam].v = *(const float4*)(xp + 64 * gam + 16 * wt + 4 * g);
    }
    __syncthreads();

    for (int t = 0; t < SEQL; ++t) {
        const int p = t & 1;

        B8u bh[2], bl[2];
        #pragma unroll
        for (int ks = 0; ks < 2; ++ks) {
            const int sl = (4 * ks + g) ^ (c & 7);
            bh[ks].q = *(const uint4*)&Hh[p][c][sl * 8];
            bl[ks].q = *(const uint4*)&Hl[p][c][sl * 8];
        }

        f32x4 a0[3], a1[3];
        #pragma unroll
        for (int gam = 0; gam < 3; ++gam) {
            a0[gam] = (f32x4){bg[gam][0], bg[gam][1], bg[gam][2], bg[gam][3]};
            a1[gam] = (f32x4){0.f, 0.f, 0.f, 0.f};
        }
        #pragma unroll
        for (int gam = 0; gam < 3; ++gam) {
            a0[gam] = __builtin_amdgcn_mfma_f32_16x16x32_bf16(awh[gam][0].v, bh[0].v, a0[gam], 0, 0, 0);
            a1[gam] = __builtin_amdgcn_mfma_f32_16x16x32_bf16(awh[gam][1].v, bh[1].v, a1[gam], 0, 0, 0);
            a0[gam] = __builtin_amdgcn_mfma_f32_16x16x32_bf16(awl[gam][0].v, bh[0].v, a0[gam], 0, 0, 0);
            a1[gam] = __builtin_amdgcn_mfma_f32_16x16x32_bf16(awl[gam][1].v, bh[1].v, a1[gam], 0, 0, 0);
            a0[gam] = __builtin_amdgcn_mfma_f32_16x16x32_bf16(awh[gam][0].v, bl[0].v, a0[gam], 0, 0, 0);
            a1[gam] = __builtin_amdgcn_mfma_f32_16x16x32_bf16(awh[gam][1].v, bl[1].v, a1[gam], 0, 0, 0);
        }

        F4u ngi[3];
        {
            const int tn = (t + 1 < SEQL) ? t + 1 : t;
            const float* xp = X + ((size_t)tn * NB + b0 + c) * 192;
            #pragma unroll
            for (int gam = 0; gam < 3; ++gam)
                ngi[gam].v = *(const float4*)(xp + 64 * gam + 16 * wt + 4 * g);
        }

        float hn4[4];
        #pragma unroll
        for (int r = 0; r < 4; ++r) {
            const float gr = a0[0][r] + a1[0][r];
            const float gz = a0[1][r] + a1[1][r];
            const float gn = a0[2][r] + a1[2][r];
            const float rr = fast_sig(gi[0].f[r] + gr);
            const float zz = fast_sig(gi[1].f[r] + gz);
            const float nn = fast_tanh(gi[2].f[r] + rr * gn);
            hn4[r] = (1.f - zz) * nn + zz * hold[r];
            hold[r] = hn4[r];
        }

        {
            const size_t row = out_batch_major ? ((size_t)(b0 + c) * SEQL + t)
                                               : ((size_t)t * NB + b0 + c);
            *(float4*)&Y[row * 64 + 16 * wt + 4 * g] =
                make_float4(hn4[0], hn4[1], hn4[2], hn4[3]);
        }

        {
            ushort hh[4], hl[4];
            #pragma unroll
            for (int r = 0; r < 4; ++r) {
                ushort h = f2bf(hn4[r]);
                hh[r] = h;
                hl[r] = f2bf(hn4[r] - __uint_as_float(((uint)h) << 16));
            }
            const int sl = (2 * wt + (g >> 1)) ^ (c & 7);
            const int ad = sl * 8 + (g & 1) * 4;
            *(uint2*)&Hh[p ^ 1][c][ad] = make_uint2((uint)hh[0] | ((uint)hh[1] << 16),
                                                    (uint)hh[2] | ((uint)hh[3] << 16));
            *(uint2*)&Hl[p ^ 1][c][ad] = make_uint2((uint)hl[0] | ((uint)hl[1] << 16),
                                                    (uint)hl[2] | ((uint)hl[3] << 16));
        }
        #pragma unroll
        for (int gam = 0; gam < 3; ++gam) gi[gam].v = ngi[gam].v;

        asm volatile("s_waitcnt lgkmcnt(0)" ::: "memory");
        __builtin_amdgcn_sched_barrier(0);
        __builtin_amdgcn_s_barrier();
        __builtin_amdgcn_sched_barrier(0);
    }
}

// ---------------------------------------------------------------------------
// MFMA GEMM, K=64, fp32 output (QKV / inter-layer projections)
// ---------------------------------------------------------------------------
template<int NCOLS>
__global__ __launch_bounds__(256, 2) void gemm_mfma(
    const float* __restrict__ A, const ushort* __restrict__ Whi,
    const ushort* __restrict__ Wlo, const float* __restrict__ bias,
    float* __restrict__ C)
{
    const int tid = threadIdx.x;
    const int w   = tid >> 6;
    const int lane = tid & 63;
    const int c = lane & 15;
    const int g = lane >> 4;
    const int m0 = blockIdx.x * 128 + 32 * w;

    B8u ah[2][2], al[2][2];
    #pragma unroll
    for (int rm = 0; rm < 2; ++rm) {
        const float* ap = A + (size_t)(m0 + 16 * rm + c) * 64;
        #pragma unroll
        for (int ks = 0; ks < 2; ++ks) {
            float4 v0 = *(const float4*)(ap + 32 * ks + 8 * g);
            float4 v1 = *(const float4*)(ap + 32 * ks + 8 * g + 4);
            split8(v0, v1, ah[rm][ks], al[rm][ks]);
        }
    }

    f32x4 acc[NCOLS / 16][2];
    #pragma unroll
    for (int nt = 0; nt < NCOLS / 16; ++nt) {
        float bv = bias[16 * nt + c];
        #pragma unroll
        for (int rm = 0; rm < 2; ++rm)
            acc[nt][rm] = (f32x4){bv, bv, bv, bv};
    }

    #pragma unroll
    for (int nt = 0; nt < NCOLS / 16; ++nt) {
        B8u wh[2], wl[2];
        #pragma unroll
        for (int ks = 0; ks < 2; ++ks) {
            size_t off = (size_t)(16 * nt + c) * 64 + 32 * ks + 8 * g;
            wh[ks].q = *(const uint4*)(Whi + off);
            wl[ks].q = *(const uint4*)(Wlo + off);
        }
        #pragma unroll
        for (int rm = 0; rm < 2; ++rm)
            #pragma unroll
            for (int ks = 0; ks < 2; ++ks) {
                acc[nt][rm] = __builtin_amdgcn_mfma_f32_16x16x32_bf16(ah[rm][ks].v, wh[ks].v, acc[nt][rm], 0, 0, 0);
                acc[nt][rm] = __builtin_amdgcn_mfma_f32_16x16x32_bf16(al[rm][ks].v, wh[ks].v, acc[nt][rm], 0, 0, 0);
                acc[nt][rm] = __builtin_amdgcn_mfma_f32_16x16x32_bf16(ah[rm][ks].v, wl[ks].v, acc[nt][rm], 0, 0, 0);
            }
    }

    #pragma unroll
    for (int nt = 0; nt < NCOLS / 16; ++nt)
        #pragma unroll
        for (int rm = 0; rm < 2; ++rm)
            #pragma unroll
            for (int reg = 0; reg < 4; ++reg) {
                int row = m0 + 16 * rm + 4 * g + reg;
                C[(size_t)row * NCOLS + 16 * nt + c] = acc[nt][rm][reg];
            }
}

// ---------------------------------------------------------------------------
// FUSED: GEMM (K=64, NCOLS=64) + residual add + LayerNorm.
// ---------------------------------------------------------------------------
__global__ __launch_bounds__(256, 2) void gemm_ln_mfma(
    const float* __restrict__ A, const ushort* __restrict__ Whi,
    const ushort* __restrict__ Wlo, const float* __restrict__ bias,
    const float* __restrict__ resid,
    const float* __restrict__ lns, const float* __restrict__ lnb,
    float* __restrict__ O)
{
    const int tid = threadIdx.x;
    const int w   = tid >> 6;
    const int lane = tid & 63;
    const int c = lane & 15;
    const int g = lane >> 4;
    const int m0 = blockIdx.x * 128 + 32 * w;

    B8u ah[2][2], al[2][2];
    #pragma unroll
    for (int rm = 0; rm < 2; ++rm) {
        const float* ap = A + (size_t)(m0 + 16 * rm + c) * 64;
        #pragma unroll
        for (int ks = 0; ks < 2; ++ks) {
            float4 v0 = *(const float4*)(ap + 32 * ks + 8 * g);
            float4 v1 = *(const float4*)(ap + 32 * ks + 8 * g + 4);
            split8(v0, v1, ah[rm][ks], al[rm][ks]);
        }
    }

    f32x4 acc[4][2];
    #pragma unroll
    for (int nt = 0; nt < 4; ++nt) {
        float bv = bias[16 * nt + c];
        #pragma unroll
        for (int rm = 0; rm < 2; ++rm)
            acc[nt][rm] = (f32x4){bv, bv, bv, bv};
    }

    #pragma unroll
    for (int nt = 0; nt < 4; ++nt) {
        B8u wh[2], wl[2];
        #pragma unroll
        for (int ks = 0; ks < 2; ++ks) {
            size_t off = (size_t)(16 * nt + c) * 64 + 32 * ks + 8 * g;
            wh[ks].q = *(const uint4*)(Whi + off);
            wl[ks].q = *(const uint4*)(Wlo + off);
        }
        #pragma unroll
        for (int rm = 0; rm < 2; ++rm)
            #pragma unroll
            for (int ks = 0; ks < 2; ++ks) {
                acc[nt][rm] = __builtin_amdgcn_mfma_f32_16x16x32_bf16(ah[rm][ks].v, wh[ks].v, acc[nt][rm], 0, 0, 0);
                acc[nt][rm] = __builtin_amdgcn_mfma_f32_16x16x32_bf16(al[rm][ks].v, wh[ks].v, acc[nt][rm], 0, 0, 0);
                acc[nt][rm] = __builtin_amdgcn_mfma_f32_16x16x32_bf16(ah[rm][ks].v, wl[ks].v, acc[nt][rm], 0, 0, 0);
            }
    }

    float vv[4][2][4];
    #pragma unroll
    for (int nt = 0; nt < 4; ++nt)
        #pragma unroll
        for (int rm = 0; rm < 2; ++rm)
            #pragma unroll
            for (int reg = 0; reg < 4; ++reg) {
                const int row = m0 + 16 * rm + 4 * g + reg;
                const float a = acc[nt][rm][reg];
                const float r_ = resid ? resid[(size_t)row * 64 + 16 * nt + c] : a;
                vv[nt][rm][reg] = a + r_;
            }

    float sv[4], bv[4];
    #pragma unroll
    for (int nt = 0; nt < 4; ++nt) { sv[nt] = lns[16 * nt + c]; bv[nt] = lnb[16 * nt + c]; }

    #pragma unroll
    for (int rm = 0; rm < 2; ++rm)
        #pragma unroll
        for (int reg = 0; reg < 4; ++reg) {
            float sum = vv[0][rm][reg] + vv[1][rm][reg] + vv[2][rm][reg] + vv[3][rm][reg];
            float sq  = vv[0][rm][reg]*vv[0][rm][reg] + vv[1][rm][reg]*vv[1][rm][reg]
                      + vv[2][rm][reg]*vv[2][rm][reg] + vv[3][rm][reg]*vv[3][rm][reg];
            #pragma unroll
            for (int off = 1; off < 16; off <<= 1) {
                sum += __shfl_xor(sum, off);
                sq  += __shfl_xor(sq,  off);
            }
            const float mean = sum * (1.f / 64.f);
            const float var  = sq * (1.f / 64.f) - mean * mean;
            const float inv  = rsqrtf(var + 1e-5f);
            const int row = m0 + 16 * rm + 4 * g + reg;
            #pragma unroll
            for (int nt = 0; nt < 4; ++nt)
                O[(size_t)row * 64 + 16 * nt + c] =
                    (vv[nt][rm][reg] - mean) * inv * sv[nt] + bv[nt];
        }
}

// ---------------------------------------------------------------------------
// FUSED: FFN + residual + LayerNorm.
// ---------------------------------------------------------------------------
__global__ __launch_bounds__(256, 2) void ffn_ln_mfma(
    const float* __restrict__ Xin,
    const ushort* __restrict__ W1hi, const ushort* __restrict__ W1lo,
    const ushort* __restrict__ W2hi, const ushort* __restrict__ W2lo,
    const float* __restrict__ b1, const float* __restrict__ b2,
    const float* __restrict__ lns, const float* __restrict__ lnb,
    float* __restrict__ Out)
{
    __shared__ __align__(16) ushort sW1h[64 * 72], sW1l[64 * 72];
    __shared__ __align__(16) ushort sW2h[64 * 72], sW2l[64 * 72];
    __shared__ __align__(16) ushort sHh[128 * 72], sHl[128 * 72];
    __shared__ float sb1[64];

    const int tid = threadIdx.x;
    const int w   = tid >> 6;
    const int lane = tid & 63;
    const int c = lane & 15;
    const int g = lane >> 4;
    const int r0 = blockIdx.x * 128;

    B8u xh[2][2], xl[2][2];
    #pragma unroll
    for (int rm = 0; rm < 2; ++rm) {
        const float* ap = Xin + (size_t)(r0 + 32 * w + 16 * rm + c) * 64;
        #pragma unroll
        for (int ks = 0; ks < 2; ++ks) {
            float4 v0 = *(const float4*)(ap + 32 * ks + 8 * g);
            float4 v1 = *(const float4*)(ap + 32 * ks + 8 * g + 4);
            split8(v0, v1, xh[rm][ks], xl[rm][ks]);
        }
    }

    f32x4 acc2[4][2];
    #pragma unroll
    for (int jt = 0; jt < 4; ++jt) {
        float bv = b2[16 * jt + c];
        #pragma unroll
        for (int mt = 0; mt < 2; ++mt)
            acc2[jt][mt] = (f32x4){bv, bv, bv, bv};
    }

    for (int nc = 0; nc < 16; ++nc) {
        __syncthreads();
        {
            const int n = tid >> 2, s = tid & 3;
            size_t s1 = (size_t)(nc * 64 + n) * 64 + s * 16;
            size_t s2 = (size_t)n * 1024 + nc * 64 + s * 16;
            int d = n * 72 + s * 16;
            *(uint4*)&sW1h[d]     = *(const uint4*)(W1hi + s1);
            *(uint4*)&sW1h[d + 8] = *(const uint4*)(W1hi + s1 + 8);
            *(uint4*)&sW1l[d]     = *(const uint4*)(W1lo + s1);
            *(uint4*)&sW1l[d + 8] = *(const uint4*)(W1lo + s1 + 8);
            *(uint4*)&sW2h[d]     = *(const uint4*)(W2hi + s2);
            *(uint4*)&sW2h[d + 8] = *(const uint4*)(W2hi + s2 + 8);
            *(uint4*)&sW2l[d]     = *(const uint4*)(W2lo + s2);
            *(uint4*)&sW2l[d + 8] = *(const uint4*)(W2lo + s2 + 8);
            if (tid < 64) sb1[tid] = b1[nc * 64 + tid];
        }
        __syncthreads();

        f32x4 acc1[4][2];
        #pragma unroll
        for (int jm = 0; jm < 4; ++jm) {
            float b0 = sb1[16 * jm + 4 * g + 0];
            float b1v = sb1[16 * jm + 4 * g + 1];
            float b2v = sb1[16 * jm + 4 * g + 2];
            float b3v = sb1[16 * jm + 4 * g + 3];
            #pragma unroll
            for (int rm = 0; rm < 2; ++rm)
                acc1[jm][rm] = (f32x4){b0, b1v, b2v, b3v};
        }
        #pragma unroll
        for (int jm = 0; jm < 4; ++jm) {
            B8u w1h[2], w1l[2];
            #pragma unroll
            for (int ks = 0; ks < 2; ++ks) {
                int off = (16 * jm + c) * 72 + 32 * ks + 8 * g;
                w1h[ks].q = *(const uint4*)&sW1h[off];
                w1l[ks].q = *(const uint4*)&sW1l[off];
            }
            #pragma unroll
            for (int rm = 0; rm < 2; ++rm)
                #pragma unroll
                for (int ks = 0; ks < 2; ++ks) {
                    acc1[jm][rm] = __builtin_amdgcn_mfma_f32_16x16x32_bf16(w1h[ks].v, xh[rm][ks].v, acc1[jm][rm], 0, 0, 0);
                    acc1[jm][rm] = __builtin_amdgcn_mfma_f32_16x16x32_bf16(w1l[ks].v, xh[rm][ks].v, acc1[jm][rm], 0, 0, 0);
                    acc1[jm][rm] = __builtin_amdgcn_mfma_f32_16x16x32_bf16(w1h[ks].v, xl[rm][ks].v, acc1[jm][rm], 0, 0, 0);
                }
        }
        #pragma unroll
        for (int jm = 0; jm < 4; ++jm)
            #pragma unroll
            for (int rm = 0; rm < 2; ++rm) {
                ushort hh[4], hl[4];
                #pragma unroll
                for (int reg = 0; reg < 4; ++reg) {
                    float hv = fmaxf(acc1[jm][rm][reg], 0.f);
                    ushort h = f2bf(hv);
                    hh[reg] = h;
                    float fh = __uint_as_float(((uint)h) << 16);
                    hl[reg] = f2bf(hv - fh);
                }
                int el = (32 * w + 16 * rm + c) * 72 + 16 * jm + 4 * g;
                *(uint2*)&sHh[el] = make_uint2((uint)hh[0] | ((uint)hh[1] << 16),
                                               (uint)hh[2] | ((uint)hh[3] << 16));
                *(uint2*)&sHl[el] = make_uint2((uint)hl[0] | ((uint)hl[1] << 16),
                                               (uint)hl[2] | ((uint)hl[3] << 16));
            }
        asm volatile("s_waitcnt lgkmcnt(0)" ::: "memory");
        __builtin_amdgcn_sched_barrier(0);

        #pragma unroll
        for (int ks = 0; ks < 2; ++ks) {
            B8u ahh[2], ahl[2], bwh[4], bwl[4];
            #pragma unroll
            for (int mt = 0; mt < 2; ++mt) {
                int el = (32 * w + 16 * mt + c) * 72 + 32 * ks + 8 * g;
                ahh[mt].q = *(const uint4*)&sHh[el];
                ahl[mt].q = *(const uint4*)&sHl[el];
            }
            #pragma unroll
            for (int jt = 0; jt < 4; ++jt) {
                int el = (16 * jt + c) * 72 + 32 * ks + 8 * g;
                bwh[jt].q = *(const uint4*)&sW2h[el];
                bwl[jt].q = *(const uint4*)&sW2l[el];
            }
            #pragma unroll
            for (int jt = 0; jt < 4; ++jt)
                #pragma unroll
                for (int mt = 0; mt < 2; ++mt) {
                    acc2[jt][mt] = __builtin_amdgcn_mfma_f32_16x16x32_bf16(ahh[mt].v, bwh[jt].v, acc2[jt][mt], 0, 0, 0);
                    acc2[jt][mt] = __builtin_amdgcn_mfma_f32_16x16x32_bf16(ahl[mt].v, bwh[jt].v, acc2[jt][mt], 0, 0, 0);
                    acc2[jt][mt] = __builtin_amdgcn_mfma_f32_16x16x32_bf16(ahh[mt].v, bwl[jt].v, acc2[jt][mt], 0, 0, 0);
                }
        }
    }

    float vv[4][2][4];
    #pragma unroll
    for (int jt = 0; jt < 4; ++jt)
        #pragma unroll
        for (int mt = 0; mt < 2; ++mt)
            #pragma unroll
            for (int reg = 0; reg < 4; ++reg) {
                const int row = r0 + 32 * w + 16 * mt + 4 * g + reg;
                vv[jt][mt][reg] = fmaxf(acc2[jt][mt][reg], 0.f) +
                                  Xin[(size_t)row * 64 + 16 * jt + c];
            }

    float sv[4], bv[4];
    #pragma unroll
    for (int jt = 0; jt < 4; ++jt) { sv[jt] = lns[16 * jt + c]; bv[jt] = lnb[16 * jt + c]; }

    #pragma unroll
    for (int mt = 0; mt < 2; ++mt)
        #pragma unroll
        for (int reg = 0; reg < 4; ++reg) {
            float sum = vv[0][mt][reg] + vv[1][mt][reg] + vv[2][mt][reg] + vv[3][mt][reg];
            float sq  = vv[0][mt][reg]*vv[0][mt][reg] + vv[1][mt][reg]*vv[1][mt][reg]
                      + vv[2][mt][reg]*vv[2][mt][reg] + vv[3][mt][reg]*vv[3][mt][reg];
            #pragma unroll
            for (int off = 1; off < 16; off <<= 1) {
                sum += __shfl_xor(sum, off);
                sq  += __shfl_xor(sq,  off);
            }
            const float mean = sum * (1.f / 64.f);
            const float var  = sq * (1.f / 64.f) - mean * mean;
            const float inv  = rsqrtf(var + 1e-5f);
            const int row = r0 + 32 * w + 16 * mt + 4 * g + reg;
            #pragma unroll
            for (int jt = 0; jt < 4; ++jt)
                Out[(size_t)row * 64 + 16 * jt + c] =
                    (vv[jt][mt][reg] - mean) * inv * sv[jt] + bv[jt];
        }
}

// ---------------------------------------------------------------------------
// MFMA flash attention (r13 version: fp32 QKV, split in-kernel)
// ---------------------------------------------------------------------------
__global__ __launch_bounds__(256, 2) void attn_mfma(
    const float* __restrict__ QKV, float* __restrict__ Out)
{
    __shared__ __align__(16) ushort Ph[4][4096];
    __shared__ __align__(16) ushort Pl[4][4096];

    const int h = blockIdx.x;
    const int b = blockIdx.y;
    const int tid = threadIdx.x;
    const int w = tid >> 6;
    const int lane = tid & 63;
    const int c = lane & 15;
    const int g = lane >> 4;
    const float scale = 0.17677669529663687f; // 1/sqrt(32)

    const float* base = QKV + (size_t)b * SEQL * 192;
    ushort* phw = Ph[w];
    ushort* plw = Pl[w];

    B8u qh[4], ql[4];
    #pragma unroll
    for (int qt = 0; qt < 4; ++qt) {
        const float* p = base + (size_t)(64 * w + 16 * qt + c) * 192 + h * 32 + 8 * g;
        float4 v0 = *(const float4*)p;
        float4 v1 = *(const float4*)(p + 4);
        v0.x *= scale; v0.y *= scale; v0.z *= scale; v0.w *= scale;
        v1.x *= scale; v1.y *= scale; v1.z *= scale; v1.w *= scale;
        split8(v0, v1, qh[qt], ql[qt]);
    }

    f32x4 o[2][4];
    #pragma unroll
    for (int dt = 0; dt < 2; ++dt)
        #pragma unroll
        for (int qt = 0; qt < 4; ++qt)
            o[dt][qt] = (f32x4){0.f, 0.f, 0.f, 0.f};
    float mrun[4] = {-1e30f, -1e30f, -1e30f, -1e30f};
    float lrun[4] = {0.f, 0.f, 0.f, 0.f};

    for (int kc = 0; kc < 4; ++kc) {
        B8u kh[4], kl[4];
        #pragma unroll
        for (int kt = 0; kt < 4; ++kt) {
            const float* p = base + (size_t)(kc * 64 + 16 * kt + c) * 192 + 64 + h * 32 + 8 * g;
            split8(*(const float4*)p, *(const float4*)(p + 4), kh[kt], kl[kt]);
        }
        f32x4 st[4][4];
        #pragma unroll
        for (int kt = 0; kt < 4; ++kt)
            #pragma unroll
            for (int qt = 0; qt < 4; ++qt)
                st[kt][qt] = (f32x4){0.f, 0.f, 0.f, 0.f};
        #pragma unroll
        for (int kt = 0; kt < 4; ++kt)
            #pragma unroll
            for (int qt = 0; qt < 4; ++qt) {
                st[kt][qt] = __builtin_amdgcn_mfma_f32_16x16x32_bf16(kh[kt].v, qh[qt].v, st[kt][qt], 0, 0, 0);
                st[kt][qt] = __builtin_amdgcn_mfma_f32_16x16x32_bf16(kl[kt].v, qh[qt].v, st[kt][qt], 0, 0, 0);
                st[kt][qt] = __builtin_amdgcn_mfma_f32_16x16x32_bf16(kh[kt].v, ql[qt].v, st[kt][qt], 0, 0, 0);
            }

        asm volatile("s_waitcnt lgkmcnt(0)" ::: "memory");
        #pragma unroll
        for (int qt = 0; qt < 4; ++qt) {
            float cmax = st[0][qt][0];
            #pragma unroll
            for (int kt = 0; kt < 4; ++kt)
                #pragma unroll
                for (int r = 0; r < 4; ++r) cmax = fmaxf(cmax, st[kt][qt][r]);
            cmax = fmaxf(cmax, __shfl_xor(cmax, 16));
            cmax = fmaxf(cmax, __shfl_xor(cmax, 32));
            const float mnew = fmaxf(mrun[qt], cmax);
            const float corr = __expf(mrun[qt] - mnew);
            mrun[qt] = mnew;
            const int ql_ = 16 * qt + c;
            float csum = 0.f;
            #pragma unroll
            for (int kt = 0; kt < 4; ++kt) {
                ushort hh[4], hl[4];
                #pragma unroll
                for (int r = 0; r < 4; ++r) {
                    float pv = __expf(st[kt][qt][r] - mnew);
                    csum += pv;
                    ushort ph_ = f2bf(pv);
                    hh[r] = ph_;
                    hl[r] = f2bf(pv - __uint_as_float(((uint)ph_) << 16));
                }
                const int ow = (2 * kt + (g >> 1)) ^ (ql_ & 7);
                const int addr = ql_ * 64 + ow * 8 + (g & 1) * 4;
                *(uint2*)&phw[addr] = make_uint2((uint)hh[0] | ((uint)hh[1] << 16),
                                                 (uint)hh[2] | ((uint)hh[3] << 16));
                *(uint2*)&plw[addr] = make_uint2((uint)hl[0] | ((uint)hl[1] << 16),
                                                 (uint)hl[2] | ((uint)hl[3] << 16));
            }
            csum += __shfl_xor(csum, 16);
            csum += __shfl_xor(csum, 32);
            lrun[qt] = lrun[qt] * corr + csum;
            #pragma unroll
            for (int dt = 0; dt < 2; ++dt)
                #pragma unroll
                for (int r = 0; r < 4; ++r) o[dt][qt][r] *= corr;
        }

        B8u vh[2][2], vl[2][2];
        #pragma unroll
        for (int ks = 0; ks < 2; ++ks)
            #pragma unroll
            for (int dt = 0; dt < 2; ++dt) {
                const float* vp = base + (size_t)(kc * 64 + ks * 32 + 8 * g) * 192 + 128 + h * 32 + 16 * dt + c;
                float f0 = vp[0], f1 = vp[192], f2 = vp[384], f3 = vp[576];
                float f4 = vp[768], f5 = vp[960], f6 = vp[1152], f7 = vp[1344];
                split8(make_float4(f0, f1, f2, f3), make_float4(f4, f5, f6, f7),
                       vh[ks][dt], vl[ks][dt]);
            }

        asm volatile("s_waitcnt lgkmcnt(0)" ::: "memory");
        __builtin_amdgcn_sched_barrier(0);

        #pragma unroll
        for (int ks = 0; ks < 2; ++ks)
            #pragma unroll
            for (int qt = 0; qt < 4; ++qt) {
                const int ql_ = 16 * qt + c;
                const int orr = (ks * 4 + g) ^ (ql_ & 7);
                const int addr = ql_ * 64 + orr * 8;
                B8u pbh, pbl;
                pbh.q = *(const uint4*)&phw[addr];
                pbl.q = *(const uint4*)&plw[addr];
                #pragma unroll
                for (int dt = 0; dt < 2; ++dt) {
                    o[dt][qt] = __builtin_amdgcn_mfma_f32_16x16x32_bf16(vh[ks][dt].v, pbh.v, o[dt][qt], 0, 0, 0);
                    o[dt][qt] = __builtin_amdgcn_mfma_f32_16x16x32_bf16(vl[ks][dt].v, pbh.v, o[dt][qt], 0, 0, 0);
                    o[dt][qt] = __builtin_amdgcn_mfma_f32_16x16x32_bf16(vh[ks][dt].v, pbl.v, o[dt][qt], 0, 0, 0);
                }
            }
    }

    #pragma unroll
    for (int qt = 0; qt < 4; ++qt) {
        const float inv = 1.f / lrun[qt];
        const size_t row = (size_t)b * SEQL + 64 * w + 16 * qt + c;
        #pragma unroll
        for (int dt = 0; dt < 2; ++dt)
            #pragma unroll
            for (int r = 0; r < 4; ++r)
                Out[row * 64 + h * 32 + 16 * dt + 4 * g + r] = o[dt][qt][r] * inv;
    }
}

// ---------------------------------------------------------------------------
// Head MLP over last timestep: 64 ->256 ->64 ->32 ->1 (silu x3)
// ---------------------------------------------------------------------------
__global__ __launch_bounds__(256) void head_kernel(
    const float* __restrict__ Hf,
    const float* __restrict__ fw1, const float* __restrict__ fb1,
    const float* __restrict__ fw2, const float* __restrict__ fb2,
    const float* __restrict__ fw3, const float* __restrict__ fb3,
    const float* __restrict__ fw4, const float* __restrict__ fb4,
    float* __restrict__ out)
{
    const int b = blockIdx.x;
    const int tid = threadIdx.x;
    __shared__ float t0[64], t1[256], t2[64], t3[32];
    if (tid < 64) t0[tid] = Hf[((size_t)b * SEQL + (SEQL - 1)) * 64 + tid];
    __syncthreads();
    {
        float acc = fb1[tid];
        #pragma unroll 4
        for (int k = 0; k < 64; ++k) acc += t0[k] * fw1[tid * 64 + k];
        t1[tid] = acc / (1.f + __expf(-acc));
    }
    __syncthreads();
    if (tid < 64) {
        float acc = fb2[tid];
        #pragma unroll 4
        for (int k = 0; k < 256; ++k) acc += t1[k] * fw2[tid * 256 + k];
        t2[tid] = acc / (1.f + __expf(-acc));
    }
    __syncthreads();
    if (tid < 32) {
        float acc = fb3[tid];
        #pragma unroll 4
        for (int k = 0; k < 64; ++k) acc += t2[k] * fw3[tid * 64 + k];
        t3[tid] = acc / (1.f + __expf(-acc));
    }
    __syncthreads();
    if (tid == 0) {
        float acc = fb4[0];
        #pragma unroll
        for (int k = 0; k < 32; ++k) acc += t3[k] * fw4[k];
        out[b] = acc;
    }
}

// ---------------------------------------------------------------------------
extern "C" void kernel_launch(void* const* d_in, const int* in_sizes, int n_in,
                              void* d_out, int out_size, void* d_ws, size_t ws_size,
                              hipStream_t stream) {
    const float* x     = (const float*)d_in[0];
    const float* emb   = (const float*)d_in[1];
    const float* wih0  = (const float*)d_in[2];
    const float* whh0  = (const float*)d_in[3];
    const float* bih0  = (const float*)d_in[4];
    const float* bhh0  = (const float*)d_in[5];
    const float* wih12 = (const float*)d_in[6];
    const float* whh12 = (const float*)d_in[7];
    const float* bih12 = (const float*)d_in[8];
    const float* bhh12 = (const float*)d_in[9];
    const float* in_w1 = (const float*)d_in[10];
    const float* in_b1 = (const float*)d_in[11];
    const float* out_w1= (const float*)d_in[12];
    const float* out_b1= (const float*)d_in[13];
    const float* in_w2 = (const float*)d_in[14];
    const float* in_b2 = (const float*)d_in[15];
    const float* out_w2= (const float*)d_in[16];
    const float* out_b2= (const float*)d_in[17];
    const float* ff_w1 = (const float*)d_in[18];
    const float* ff_b1 = (const float*)d_in[19];
    const float* ff_w2 = (const float*)d_in[20];
    const float* ff_b2 = (const float*)d_in[21];
    const float* ln1_s = (const float*)d_in[22];
    const float* ln1_b = (const float*)d_in[23];
    const float* ln2_s = (const float*)d_in[24];
    const float* ln2_b = (const float*)d_in[25];
    const float* ln3_s = (const float*)d_in[26];
    const float* ln3_b = (const float*)d_in[27];
    const float* ln4_s = (const float*)d_in[28];
    const float* ln4_b = (const float*)d_in[29];
    const float* fw1   = (const float*)d_in[30];
    const float* fb1   = (const float*)d_in[31];
    const float* fw2   = (const float*)d_in[32];
    const float* fb2   = (const float*)d_in[33];
    const float* fw3   = (const float*)d_in[34];
    const float* fb3   = (const float*)d_in[35];
    const float* fw4   = (const float*)d_in[36];
    const float* fb4   = (const float*)d_in[37];

    float* ws = (float*)d_ws;
    float* X  = ws;                       // 98304*192 fp32
    float* S0 = X  + (size_t)NROWS * 192; // 98304*64
    float* S1 = S0 + (size_t)NROWS * 64;
    float* S2 = S1 + (size_t)NROWS * 64;

    ushort* bf = (ushort*)(S2 + (size_t)NROWS * 64);
    ushort* ffw1hi = bf;               // 65536
    ushort* ffw1lo = ffw1hi + 65536;
    ushort* ffw2hi = ffw1lo + 65536;   // 65536
    ushort* ffw2lo = ffw2hi + 65536;
    ushort* wghi   = ffw2lo + 65536;   // 24576 (wih12: 2 layers x 192 x 64)
    ushort* wglo   = wghi + 24576;
    ushort* q1hi   = wglo + 24576;     // 12288
    ushort* q1lo   = q1hi + 12288;
    ushort* q2hi   = q1lo + 12288;
    ushort* q2lo   = q2hi + 12288;
    ushort* o1hi   = q2lo + 12288;     // 4096
    ushort* o1lo   = o1hi + 4096;
    ushort* o2hi   = o1lo + 4096;
    ushort* o2lo   = o2hi + 4096;
    ushort* w0hi   = o2lo + 4096;      // whh0: 12288
    ushort* w0lo   = w0hi + 12288;
    ushort* w12hi  = w0lo + 12288;     // whh12: 24576 (2 layers)
    ushort* w12lo  = w12hi + 24576;

    // ---- weight splits + featurize/proj0 in ONE launch ----
    prep_kernel<<<880 + NROWS / 32, 256, 0, stream>>>(
        ff_w1, ff_w2, wih12, in_w1, in_w2, out_w1, out_w2, whh0, whh12,
        ffw1hi, ffw2hi, wghi, q1hi, q2hi, o1hi, o2hi, w0hi, w12hi,
        ffw1lo, ffw2lo, wglo, q1lo, q2lo, o1lo, o2lo, w0lo, w12lo,
        x, emb, wih0, bih0, X);

    // ---- GRU stack (r13 config: 16 rows/block, 24 blocks) ----
    gru_mfma<<<NB / 16, 256, 0, stream>>>(X, w0hi, w0lo, bhh0, S0, 0);
    gemm_mfma<192><<<NROWS / 128, 256, 0, stream>>>(S0, wghi, wglo, bih12, X);
    gru_mfma<<<NB / 16, 256, 0, stream>>>(X, w12hi, w12lo, bhh12, S1, 0);
    gemm_mfma<192><<<NROWS / 128, 256, 0, stream>>>(S1, wghi + 12288, wglo + 12288, bih12 + 192, X);
    gru_mfma<<<NB / 16, 256, 0, stream>>>(X, w12hi + 12288, w12lo + 12288, bhh12 + 192, S0, 1); // g

    // ---- Transformer block 1 ----
    gemm_mfma<192><<<NROWS / 128, 256, 0, stream>>>(S0, q1hi, q1lo, in_b1, X);
    attn_mfma<<<dim3(2, NB), 256, 0, stream>>>(X, S1);
    gemm_ln_mfma<<<NROWS / 128, 256, 0, stream>>>(S1, o1hi, o1lo, out_b1,
                                                  S0, ln1_s, ln1_b, S2);     // h = LN(g + a)
    ffn_ln_mfma<<<NROWS / 128, 256, 0, stream>>>(S2, ffw1hi, ffw1lo, ffw2hi, ffw2lo,
                                                 ff_b1, ff_b2, ln2_s, ln2_b, S0); // h = LN(h+ffn)

    // ---- Transformer block 2 ----
    gemm_mfma<192><<<NROWS / 128, 256, 0, stream>>>(S0, q2hi, q2lo, in_b2, X);
    attn_mfma<<<dim3(2, NB), 256, 0, stream>>>(X, S1);
    gemm_ln_mfma<<<NROWS / 128, 256, 0, stream>>>(S1, o2hi, o2lo, out_b2,
                                                  nullptr, ln3_s, ln3_b, S2); // h = LN(a + a)
    ffn_ln_mfma<<<NROWS / 128, 256, 0, stream>>>(S2, ffw1hi, ffw1lo, ffw2hi, ffw2lo,
                                                 ff_b1, ff_b2, ln4_s, ln4_b, S1); // h = LN(h+ffn)

    // ---- Head ----
    head_kernel<<<NB, 256, 0, stream>>>(S1, fw1, fb1, fw2, fb2, fw3, fb3, fw4, fb4,
                                        (float*)d_out);
    (void)in_sizes; (void)n_in; (void)out_size; (void)ws_size;
}